// Round 7
// baseline (509.215 us; speedup 1.0000x reference)
//
#include <hip/hip_runtime.h>

#define DIM 64

typedef __attribute__((ext_vector_type(4))) float f4;
typedef __attribute__((ext_vector_type(2))) float f2;
typedef __attribute__((ext_vector_type(4))) unsigned int u4;
typedef __attribute__((ext_vector_type(2))) unsigned int u2;

#define SEL_LO 0x01000504u   // [src0.lo16 | src1.lo16<<16]
#define SEL_HI 0x03020706u   // [src0.hi16 | src1.hi16<<16]
#define ONE2   0x3f803f80u   // bf16 pair (1.0, 1.0)

// ---- bf16 helpers ----
__device__ __forceinline__ float bflo(unsigned u) { return __uint_as_float(u << 16); }
__device__ __forceinline__ float bfhi(unsigned u) { return __uint_as_float(u & 0xffff0000u); }
__device__ __forceinline__ unsigned bfr(float f) {
    unsigned u = __float_as_uint(f);
    return (u + 0x7fffu + ((u >> 16) & 1u)) >> 16;
}
__device__ __forceinline__ unsigned packbf(float e, float o) { return bfr(e) | (bfr(o) << 16); }
// packed f32->bf16 pair (RNE), lo = first arg
__device__ __forceinline__ unsigned cvtpk(float lo, float hi) {
    unsigned r;
    asm("v_cvt_pk_bf16_f32 %0, %1, %2" : "=v"(r) : "v"(lo), "v"(hi));
    return r;
}
// D = a.lo*b.lo + a.hi*b.hi + c   (bf16 pairs, f32 accumulate)
__device__ __forceinline__ float dot2bf(unsigned a, unsigned b, float c) {
    float d;
    asm("v_dot2_f32_bf16 %0, %1, %2, %3" : "=v"(d) : "v"(a), "v"(b), "v"(c));
    return d;
}
// sum within each 8-lane group
__device__ __forceinline__ float gsum8(float v) {
    v += __shfl_xor(v, 1, 64);
    v += __shfl_xor(v, 2, 64);
    v += __shfl_xor(v, 4, 64);
    return v;
}

// row_ptr[r] = lower_bound(rows, r) over sorted rows.
__global__ void build_row_ptr_kernel(const int* __restrict__ rows, int nnz,
                                     int n, int* __restrict__ row_ptr) {
    int r = blockIdx.x * blockDim.x + threadIdx.x;
    if (r > n) return;
    int lo = 0, hi = nnz;
    while (lo < hi) {
        int mid = (lo + hi) >> 1;
        if (rows[mid] < r) lo = mid + 1; else hi = mid;
    }
    row_ptr[r] = lo;
}

// f32 -> packed bf16 table, 8 elems per thread.
__global__ void cvt_bf16_kernel(const float* __restrict__ in,
                                unsigned int* __restrict__ out, int n8) {
    int i = blockIdx.x * blockDim.x + threadIdx.x;
    if (i >= n8) return;
    const f4* p = (const f4*)in + 2 * (size_t)i;
    f4 a = p[0], b = p[1];
    u4 o;
    o.x = packbf(a.x, a.y); o.y = packbf(a.z, a.w);
    o.z = packbf(b.x, b.y); o.w = packbf(b.z, b.w);
    ((u4*)out)[i] = o;
}

// One ROW per 8-lane group (8 rows/wave); lane j owns dims 8j..8j+7.
// 8 nnz per step -> 8 independent dwordx4 gathers in flight.
//
// MODE 0: e1 = A1 @ t0 -> enew; y-stats (my,svy) -> stats; b1 -> bbuf
// MODE 1: prop = A2@eprev; en = b*prop+(1-b)*t0 -> enew; b_next -> bbuf
// MODE 2: en with y0 = emb(f32); out = (emb + e1 + e2 + eprev + en)/5
template <int MODE>
__global__ __launch_bounds__(256) void layer_kernel(
    const float* __restrict__ emb,
    const unsigned short* __restrict__ t0,
    const unsigned short* __restrict__ eprev,
    const float* __restrict__ vals, const int* __restrict__ cols,
    const int* __restrict__ rp, int n,
    unsigned short* __restrict__ enew,
    const unsigned short* __restrict__ e1t,
    const unsigned short* __restrict__ e2t,
    f2* __restrict__ stats, float* __restrict__ bbuf,
    float* __restrict__ out)
{
    const int tid  = threadIdx.x;
    const int lane = tid & 63;
    const int j    = lane & 7;
    const int wave = blockIdx.x * (blockDim.x >> 6) + (tid >> 6);
    const int rowg = wave * 8 + (lane >> 3);
    const int rg   = rowg < n ? rowg : n - 1;

    const int start = rp[rg];
    const int end   = rp[rg + 1];
    const int len   = (rowg < n) ? (end - start) : 0;
    const int b0    = start & ~1;
    const int doff  = b0 - start;

    int ml = len;
    ml = max(ml, __shfl_xor(ml, 8, 64));
    ml = max(ml, __shfl_xor(ml, 16, 64));
    ml = max(ml, __shfl_xor(ml, 32, 64));
    const int steps = (ml + 8) >> 3;

    const char* tb8 = (const char*)eprev;
    const unsigned joff = (unsigned)(j << 4);
    const size_t ro = (size_t)rg << 6;

    // early loads (hide latency under the main loop)
    float bcoef = 0.f;
    if (MODE != 0) bcoef = bbuf[rg];
    u4 yr = {};
    if (MODE != 2) yr = *((const u4*)(t0 + ro) + j);
    f2 st = {};
    if (MODE == 1) st = stats[rg];

    float acc[8] = {0.f, 0.f, 0.f, 0.f, 0.f, 0.f, 0.f, 0.f};

    for (int s = 0; s < steps; ++s) {
        const int k = b0 + (s << 3);
        u2 c01 = __builtin_nontemporal_load((const u2*)(cols + k));
        u2 c23 = __builtin_nontemporal_load((const u2*)(cols + k + 2));
        u2 c45 = __builtin_nontemporal_load((const u2*)(cols + k + 4));
        u2 c67 = __builtin_nontemporal_load((const u2*)(cols + k + 6));
        f2 v01 = __builtin_nontemporal_load((const f2*)(vals + k));
        f2 v23 = __builtin_nontemporal_load((const f2*)(vals + k + 2));
        f2 v45 = __builtin_nontemporal_load((const f2*)(vals + k + 4));
        f2 v67 = __builtin_nontemporal_load((const f2*)(vals + k + 6));
        const int rel = (s << 3) + doff;
        bool ok0 = (unsigned)(rel)     < (unsigned)len;
        bool ok1 = (unsigned)(rel + 1) < (unsigned)len;
        bool ok2 = (unsigned)(rel + 2) < (unsigned)len;
        bool ok3 = (unsigned)(rel + 3) < (unsigned)len;
        bool ok4 = (unsigned)(rel + 4) < (unsigned)len;
        bool ok5 = (unsigned)(rel + 5) < (unsigned)len;
        bool ok6 = (unsigned)(rel + 6) < (unsigned)len;
        bool ok7 = (unsigned)(rel + 7) < (unsigned)len;
        unsigned cc0 = ok0 ? (unsigned)c01.x : 0u;
        unsigned cc1 = ok1 ? (unsigned)c01.y : 0u;
        unsigned cc2 = ok2 ? (unsigned)c23.x : 0u;
        unsigned cc3 = ok3 ? (unsigned)c23.y : 0u;
        unsigned cc4 = ok4 ? (unsigned)c45.x : 0u;
        unsigned cc5 = ok5 ? (unsigned)c45.y : 0u;
        unsigned cc6 = ok6 ? (unsigned)c67.x : 0u;
        unsigned cc7 = ok7 ? (unsigned)c67.y : 0u;
        // issue all 8 gathers before consuming
        u4 g0 = *(const u4*)(tb8 + ((cc0 << 7) + joff));
        u4 g1 = *(const u4*)(tb8 + ((cc1 << 7) + joff));
        u4 g2 = *(const u4*)(tb8 + ((cc2 << 7) + joff));
        u4 g3 = *(const u4*)(tb8 + ((cc3 << 7) + joff));
        u4 g4 = *(const u4*)(tb8 + ((cc4 << 7) + joff));
        u4 g5 = *(const u4*)(tb8 + ((cc5 << 7) + joff));
        u4 g6 = *(const u4*)(tb8 + ((cc6 << 7) + joff));
        u4 g7 = *(const u4*)(tb8 + ((cc7 << 7) + joff));
        float w0 = ok0 ? v01.x : 0.f;
        float w1 = ok1 ? v01.y : 0.f;
        float w2 = ok2 ? v23.x : 0.f;
        float w3 = ok3 ? v23.y : 0.f;
        float w4 = ok4 ? v45.x : 0.f;
        float w5 = ok5 ? v45.y : 0.f;
        float w6 = ok6 ? v67.x : 0.f;
        float w7 = ok7 ? v67.y : 0.f;
        unsigned vp01 = cvtpk(w0, w1);
        unsigned vp23 = cvtpk(w2, w3);
        unsigned vp45 = cvtpk(w4, w5);
        unsigned vp67 = cvtpk(w6, w7);
#define CONSUME(ga, gb, vp)                                                    \
        acc[0] = dot2bf(__builtin_amdgcn_perm(ga.x, gb.x, SEL_LO), vp, acc[0]);\
        acc[1] = dot2bf(__builtin_amdgcn_perm(ga.x, gb.x, SEL_HI), vp, acc[1]);\
        acc[2] = dot2bf(__builtin_amdgcn_perm(ga.y, gb.y, SEL_LO), vp, acc[2]);\
        acc[3] = dot2bf(__builtin_amdgcn_perm(ga.y, gb.y, SEL_HI), vp, acc[3]);\
        acc[4] = dot2bf(__builtin_amdgcn_perm(ga.z, gb.z, SEL_LO), vp, acc[4]);\
        acc[5] = dot2bf(__builtin_amdgcn_perm(ga.z, gb.z, SEL_HI), vp, acc[5]);\
        acc[6] = dot2bf(__builtin_amdgcn_perm(ga.w, gb.w, SEL_LO), vp, acc[6]);\
        acc[7] = dot2bf(__builtin_amdgcn_perm(ga.w, gb.w, SEL_HI), vp, acc[7]);
        CONSUME(g0, g1, vp01)
        CONSUME(g2, g3, vp23)
        CONSUME(g4, g5, vp45)
        CONSUME(g6, g7, vp67)
#undef CONSUME
    }

    if (MODE == 0) {
        // y-stats of t0 row
        float sy  = dot2bf(yr.x, ONE2,
                    dot2bf(yr.y, ONE2, dot2bf(yr.z, ONE2, dot2bf(yr.w, ONE2, 0.f))));
        float syy = dot2bf(yr.x, yr.x,
                    dot2bf(yr.y, yr.y, dot2bf(yr.z, yr.z, dot2bf(yr.w, yr.w, 0.f))));
        sy = gsum8(sy); syy = gsum8(syy);
        float my  = sy * (1.f / 64.f);
        float vy  = syy - sy * my;
        float svy = sqrtf(fmaxf(vy, 0.f));
        u4 o;
        o.x = cvtpk(acc[0], acc[1]); o.y = cvtpk(acc[2], acc[3]);
        o.z = cvtpk(acc[4], acc[5]); o.w = cvtpk(acc[6], acc[7]);
        // b for next layer: pearson(rounded e1, t0)
        float sx  = dot2bf(o.x, ONE2,
                    dot2bf(o.y, ONE2, dot2bf(o.z, ONE2, dot2bf(o.w, ONE2, 0.f))));
        float sxx = dot2bf(o.x, o.x,
                    dot2bf(o.y, o.y, dot2bf(o.z, o.z, dot2bf(o.w, o.w, 0.f))));
        float sxy = dot2bf(o.x, yr.x,
                    dot2bf(o.y, yr.y, dot2bf(o.z, yr.z, dot2bf(o.w, yr.w, 0.f))));
        sx = gsum8(sx); sxx = gsum8(sxx); sxy = gsum8(sxy);
        float mx  = sx * (1.f / 64.f);
        float num = sxy - sx * my;
        float vx  = sxx - sx * mx;
        float den = sqrtf(fmaxf(vx, 0.f)) * svy;
        den = fmaxf(den, 1e-7f);
        float bn = num / den;
        if (rowg < n) {
            if (j == 0) {
                f2 s2; s2.x = my; s2.y = svy;
                stats[rowg] = s2;
                bbuf[rowg]  = bn;
            }
            *((u4*)(enew + ro) + j) = o;
        }
        return;
    }

    const float ob = 1.f - bcoef;

    if (MODE == 1) {
        float y0[8] = { bflo(yr.x), bfhi(yr.x), bflo(yr.y), bfhi(yr.y),
                        bflo(yr.z), bfhi(yr.z), bflo(yr.w), bfhi(yr.w) };
        u4 o;
        o.x = cvtpk(bcoef * acc[0] + ob * y0[0], bcoef * acc[1] + ob * y0[1]);
        o.y = cvtpk(bcoef * acc[2] + ob * y0[2], bcoef * acc[3] + ob * y0[3]);
        o.z = cvtpk(bcoef * acc[4] + ob * y0[4], bcoef * acc[5] + ob * y0[5]);
        o.w = cvtpk(bcoef * acc[6] + ob * y0[6], bcoef * acc[7] + ob * y0[7]);
        // b for next layer: pearson(rounded en, t0)
        float sx  = dot2bf(o.x, ONE2,
                    dot2bf(o.y, ONE2, dot2bf(o.z, ONE2, dot2bf(o.w, ONE2, 0.f))));
        float sxx = dot2bf(o.x, o.x,
                    dot2bf(o.y, o.y, dot2bf(o.z, o.z, dot2bf(o.w, o.w, 0.f))));
        float sxy = dot2bf(o.x, yr.x,
                    dot2bf(o.y, yr.y, dot2bf(o.z, yr.z, dot2bf(o.w, yr.w, 0.f))));
        sx = gsum8(sx); sxx = gsum8(sxx); sxy = gsum8(sxy);
        float mx  = sx * (1.f / 64.f);
        float num = sxy - sx * st.x;
        float vx  = sxx - sx * mx;
        float den = sqrtf(fmaxf(vx, 0.f)) * st.y;
        den = fmaxf(den, 1e-7f);
        float bn = num / den;
        if (rowg < n) {
            if (j == 0) bbuf[rowg] = bn;
            *((u4*)(enew + ro) + j) = o;
        }
    } else {
        const f4* ep = (const f4*)(emb + ro) + 2 * j;
        f4 ea = ep[0], eb = ep[1];
        float y0[8] = { ea.x, ea.y, ea.z, ea.w, eb.x, eb.y, eb.z, eb.w };
        u4 xr = *((const u4*)(eprev + ro) + j);
        float xp[8] = { bflo(xr.x), bfhi(xr.x), bflo(xr.y), bfhi(xr.y),
                        bflo(xr.z), bfhi(xr.z), bflo(xr.w), bfhi(xr.w) };
        u4 r1 = *((const u4*)(e1t + ro) + j);
        u4 r2 = *((const u4*)(e2t + ro) + j);
        float s[8];
        s[0] = y0[0] + bflo(r1.x) + bflo(r2.x) + xp[0] + (bcoef * acc[0] + ob * y0[0]);
        s[1] = y0[1] + bfhi(r1.x) + bfhi(r2.x) + xp[1] + (bcoef * acc[1] + ob * y0[1]);
        s[2] = y0[2] + bflo(r1.y) + bflo(r2.y) + xp[2] + (bcoef * acc[2] + ob * y0[2]);
        s[3] = y0[3] + bfhi(r1.y) + bfhi(r2.y) + xp[3] + (bcoef * acc[3] + ob * y0[3]);
        s[4] = y0[4] + bflo(r1.z) + bflo(r2.z) + xp[4] + (bcoef * acc[4] + ob * y0[4]);
        s[5] = y0[5] + bfhi(r1.z) + bfhi(r2.z) + xp[5] + (bcoef * acc[5] + ob * y0[5]);
        s[6] = y0[6] + bflo(r1.w) + bflo(r2.w) + xp[6] + (bcoef * acc[6] + ob * y0[6]);
        s[7] = y0[7] + bfhi(r1.w) + bfhi(r2.w) + xp[7] + (bcoef * acc[7] + ob * y0[7]);
        if (rowg < n) {
            f4 o0 = { s[0] * 0.2f, s[1] * 0.2f, s[2] * 0.2f, s[3] * 0.2f };
            f4 o1 = { s[4] * 0.2f, s[5] * 0.2f, s[6] * 0.2f, s[7] * 0.2f };
            f4* op = (f4*)(out + ro) + 2 * j;
            op[0] = o0; op[1] = o1;
        }
    }
}

extern "C" void kernel_launch(void* const* d_in, const int* in_sizes, int n_in,
                              void* d_out, int out_size, void* d_ws, size_t ws_size,
                              hipStream_t stream) {
    const float* emb   = (const float*)d_in[0];
    const float* vals  = (const float*)d_in[1];
    const float* vals2 = (const float*)d_in[2];
    const int*   rows  = (const int*)d_in[3];
    const int*   cols  = (const int*)d_in[4];
    const int*   rows2 = (const int*)d_in[5];
    const int*   cols2 = (const int*)d_in[6];
    // n_layers = 3 (fixed for this problem)

    const int n    = in_sizes[0] / DIM;   // 300000
    const int nnz  = in_sizes[1];         // 4800000
    const int nnz2 = in_sizes[2];

    float* out = (float*)d_out;

    // ws: rp1 | rp2 | ST | BB | T0 | E1 | E2 | E3  (~160 MB)
    char*  ws       = (char*)d_ws;
    size_t rp_bytes = (((size_t)(n + 1) * sizeof(int)) + 255) & ~(size_t)255;
    size_t st_bytes = (((size_t)n * sizeof(f2)) + 255) & ~(size_t)255;
    size_t bb_bytes = (((size_t)n * sizeof(float)) + 255) & ~(size_t)255;
    size_t tb_bytes = (size_t)n * DIM * sizeof(unsigned short);
    int*   rp1 = (int*)ws;
    int*   rp2 = (int*)(ws + rp_bytes);
    f2*    ST  = (f2*)(ws + 2 * rp_bytes);
    float* BB  = (float*)(ws + 2 * rp_bytes + st_bytes);
    unsigned short* T0 = (unsigned short*)(ws + 2 * rp_bytes + st_bytes + bb_bytes);
    unsigned short* E1 = (unsigned short*)((char*)T0 + tb_bytes);
    unsigned short* E2 = (unsigned short*)((char*)E1 + tb_bytes);
    unsigned short* E3 = (unsigned short*)((char*)E2 + tb_bytes);

    const int tb = 256;
    build_row_ptr_kernel<<<(n + 1 + tb - 1) / tb, tb, 0, stream>>>(rows,  nnz,  n, rp1);
    build_row_ptr_kernel<<<(n + 1 + tb - 1) / tb, tb, 0, stream>>>(rows2, nnz2, n, rp2);

    const int n8 = n * DIM / 8;
    cvt_bf16_kernel<<<(n8 + tb - 1) / tb, tb, 0, stream>>>(emb, (unsigned int*)T0, n8);

    const int waves = (n + 7) / 8;            // 8 rows per wave
    const int grid  = (waves + 3) / 4;        // 4 waves per 256-thread block
    // e1 = A1 @ t0 ; y-stats ; b1
    layer_kernel<0><<<grid, tb, 0, stream>>>(emb, T0, T0, vals, cols, rp1, n,
                                             E1, T0, T0, ST, BB, out);
    // e2 from e1 ; b2
    layer_kernel<1><<<grid, tb, 0, stream>>>(emb, T0, E1, vals2, cols2, rp2, n,
                                             E2, T0, T0, ST, BB, out);
    // e3 from e2 ; b3
    layer_kernel<1><<<grid, tb, 0, stream>>>(emb, T0, E2, vals2, cols2, rp2, n,
                                             E3, T0, T0, ST, BB, out);
    // final: e4 from e3, fused mean -> out
    layer_kernel<2><<<grid, tb, 0, stream>>>(emb, T0, E3, vals2, cols2, rp2, n,
                                             E3, E1, E2, ST, BB, out);
}